// Round 5
// baseline (234.741 us; speedup 1.0000x reference)
//
#include <hip/hip_runtime.h>

#define B_  16
#define N_  4096
#define M_  1024
#define C1_ 128
#define C2_ 256
#define K0_ 384   // C2 + C1
#define O1_ 256
#define O2_ 256

typedef _Float16 half4  __attribute__((ext_vector_type(4)));
typedef _Float16 half8  __attribute__((ext_vector_type(8)));
typedef float    f32x4  __attribute__((ext_vector_type(4)));

// ---------------------------------------------------------------------------
// three_nn v4 (unchanged): LDS xyz2 as {x,y,z,|p|^2}, 8 chunks x 128 pts,
// 8 threads/query, exact fp32 distances, med3 sorted-insert, butterfly merge.
// ---------------------------------------------------------------------------
__global__ __launch_bounds__(256)
void three_nn_kernel(const float* __restrict__ xyz1, const float* __restrict__ xyz2,
                     int* __restrict__ idxb, float* __restrict__ wb) {
    __shared__ float pts[8 * 516];
    int b = blockIdx.y;
    int t = threadIdx.x;
    {
        const float* src = xyz2 + (size_t)b * 3 * M_;
        int m0 = t * 4;
        f32x4 xv = *(const f32x4*)(src + m0);
        f32x4 yv = *(const f32x4*)(src + M_ + m0);
        f32x4 zv = *(const f32x4*)(src + 2 * M_ + m0);
        float* dst = pts + (m0 >> 7) * 516 + (m0 & 127) * 4;
#pragma unroll
        for (int jj = 0; jj < 4; ++jj) {
            f32x4 o = {xv[jj], yv[jj], zv[jj],
                       fmaf(xv[jj], xv[jj], fmaf(yv[jj], yv[jj], zv[jj] * zv[jj]))};
            *(f32x4*)(dst + jj * 4) = o;
        }
    }
    __syncthreads();
    int lane = t & 63;
    int c = lane & 7;
    int q = ((t >> 6) << 3) + (lane >> 3);
    int n = blockIdx.x * 32 + q;
    const float* qp = xyz1 + (size_t)b * 3 * N_;
    float px = qp[n], py = qp[N_ + n], pz = qp[2 * N_ + n];
    float px2 = -2.f * px, py2 = -2.f * py, pz2 = -2.f * pz;
    const float* base = pts + c * 516;
    float b0 = 1e30f, b1v = 1e30f, b2v = 1e30f;
    int i0 = 0, i1 = 0, i2 = 0;
    int mb = c * 128;
#pragma unroll 4
    for (int i = 0; i < 128; ++i) {
        f32x4 pv = *(const f32x4*)(base + i * 4);
        float d = fmaf(pv[0], px2, fmaf(pv[1], py2, fmaf(pv[2], pz2, pv[3])));
        int m = mb + i;
        bool c0 = d < b0, c1 = d < b1v, c2 = d < b2v;
        float nb1 = __builtin_amdgcn_fmed3f(d, b0, b1v);
        float nb2 = __builtin_amdgcn_fmed3f(d, b1v, b2v);
        i2 = c1 ? i1 : (c2 ? m : i2);
        i1 = c0 ? i0 : (c1 ? m : i1);
        i0 = c0 ? m : i0;
        b0 = fminf(b0, d);
        b1v = nb1; b2v = nb2;
    }
#pragma unroll
    for (int st = 1; st <= 4; st <<= 1) {
        float d0 = __shfl_xor(b0, st, 64);  int j0 = __shfl_xor(i0, st, 64);
        float d1 = __shfl_xor(b1v, st, 64); int j1 = __shfl_xor(i1, st, 64);
        float d2 = __shfl_xor(b2v, st, 64); int j2 = __shfl_xor(i2, st, 64);
#pragma unroll
        for (int e = 0; e < 3; ++e) {
            float d = (e == 0) ? d0 : (e == 1) ? d1 : d2;
            int   m = (e == 0) ? j0 : (e == 1) ? j1 : j2;
            bool c0 = d < b0, c1 = d < b1v, c2 = d < b2v;
            float nb1 = __builtin_amdgcn_fmed3f(d, b0, b1v);
            float nb2 = __builtin_amdgcn_fmed3f(d, b1v, b2v);
            i2 = c1 ? i1 : (c2 ? m : i2);
            i1 = c0 ? i0 : (c1 ? m : i1);
            i0 = c0 ? m : i0;
            b0 = fminf(b0, d);
            b1v = nb1; b2v = nb2;
        }
    }
    if ((lane & 7) == 0) {
        float sq1 = fmaf(px, px, fmaf(py, py, pz * pz));
        float e0 = fmaxf(sqrtf(fmaxf(b0 + sq1, 1e-20f)), 1e-10f);
        float e1 = fmaxf(sqrtf(fmaxf(b1v + sq1, 1e-20f)), 1e-10f);
        float e2 = fmaxf(sqrtf(fmaxf(b2v + sq1, 1e-20f)), 1e-10f);
        float r0 = 1.f / e0, r1 = 1.f / e1, r2 = 1.f / e2;
        float s = r0 + r1 + r2;
        size_t j = ((size_t)b * N_ + n) * 3;
        idxb[j] = i0; idxb[j + 1] = i1; idxb[j + 2] = i2;
        wb[j] = r0 / s; wb[j + 1] = r1 / s; wb[j + 2] = r2 / s;
    }
}

// ---------------------------------------------------------------------------
__global__ __launch_bounds__(256)
void convert_w_kernel(const float* __restrict__ W1, const float* __restrict__ W2,
                      _Float16* __restrict__ W1h, _Float16* __restrict__ W2h) {
    int t = blockIdx.x * 256 + threadIdx.x;
    if (t < O1_ * K0_) W1h[t] = (_Float16)W1[t];
    if (t < O2_ * O1_) W2h[t] = (_Float16)W2[t];
}

// ---------------------------------------------------------------------------
// Generic (C,NP) fp32 -> (NP,C) fp16 transpose via 64x64 LDS tile.
// ---------------------------------------------------------------------------
__global__ __launch_bounds__(256)
void transpose_f16_kernel(const float* __restrict__ in, _Float16* __restrict__ out,
                          int NP, size_t in_bstride, size_t out_bstride,
                          int out_rstride) {
    __shared__ float tile[64][65];
    int t = threadIdx.x;
    int nb = blockIdx.x * 64, cb = blockIdx.y * 64;
    const float* ib = in + blockIdx.z * in_bstride;
#pragma unroll
    for (int r = 0; r < 16; ++r) {
        int cc = r * 4 + (t >> 6);
        tile[cc][t & 63] = ib[(size_t)(cb + cc) * NP + nb + (t & 63)];
    }
    __syncthreads();
    _Float16* ob = out + blockIdx.z * out_bstride;
#pragma unroll
    for (int pass = 0; pass < 2; ++pass) {
        int id = pass * 256 + t;
        int nl = id >> 3;
        int c8 = (id & 7) * 8;
        half8 v;
#pragma unroll
        for (int jj = 0; jj < 8; ++jj) v[jj] = (_Float16)tile[c8 + jj][nl];
        *(half8*)(ob + (size_t)(nb + nl) * out_rstride + cb + c8) = v;
    }
}

// ---------------------------------------------------------------------------
// Kernel A: cooperative X-stage (interp fp32-accum + points1) in 48KB LDS ->
// GEMM1(relu) -> Y1 (B,N,O1) fp16 in global.
// Block: 256 thr / 4 waves; tile 64n x 256o; wave = 64o x 64n (acc[4][4]).
// 48KB LDS -> 3 blocks/CU; launch_bounds(256,2) keeps VGPR headroom (ILP!).
// ---------------------------------------------------------------------------
__global__ __launch_bounds__(256, 2)
void gemm1_fused_kernel(const _Float16* __restrict__ p2T, const int* __restrict__ idxb,
                        const float* __restrict__ wb, const float* __restrict__ points1,
                        const _Float16* __restrict__ p1T,
                        const _Float16* __restrict__ W1h, const float* __restrict__ b1,
                        _Float16* __restrict__ Y1, int b0) {
    __shared__ char Xs[64 * 768];     // row n: 768B (384 fp16), 16B-XOR swizzled
    int b = b0 + blockIdx.y;
    int n0b = blockIdx.x * 64;
    int t = threadIdx.x;

    // ---- stage X: 4 threads per row; sub = 64-channel interp seg + 32-ch p1 seg
    {
        int row = t >> 2, sub = t & 3;
        size_t j = ((size_t)b * N_ + n0b + row) * 3;
        int i0 = idxb[j], i1 = idxb[j + 1], i2 = idxb[j + 2];
        float w0 = wb[j], w1 = wb[j + 1], w2 = wb[j + 2];
        const _Float16* pb = p2T + (size_t)b * M_ * C2_;
        const half8* q0 = (const half8*)(pb + (size_t)i0 * C2_ + sub * 64);
        const half8* q1 = (const half8*)(pb + (size_t)i1 * C2_ + sub * 64);
        const half8* q2 = (const half8*)(pb + (size_t)i2 * C2_ + sub * 64);
        int rswz = (row & 7) << 4;
        char* xrow = Xs + row * 768;
#pragma unroll
        for (int x = 0; x < 8; ++x) {
            half8 a0 = q0[x], a1 = q1[x], a2 = q2[x];
            half8 v;
#pragma unroll
            for (int jj = 0; jj < 8; ++jj)
                v[jj] = (_Float16)(w0 * (float)a0[jj] + w1 * (float)a1[jj]
                                 + w2 * (float)a2[jj]);
            *(half8*)(xrow + ((sub * 128 + x * 16) ^ rswz)) = v;
        }
        if (p1T) {
            const half8* q3 = (const half8*)(p1T + ((size_t)b * N_ + n0b + row) * C1_ + sub * 32);
#pragma unroll
            for (int x = 0; x < 4; ++x) {
                half8 v = q3[x];
                *(half8*)(xrow + ((512 + sub * 64 + x * 16) ^ rswz)) = v;
            }
        } else {
            const float* pp = points1 + ((size_t)b * C1_ + sub * 32) * N_ + n0b + row;
#pragma unroll
            for (int x = 0; x < 4; ++x) {
                half8 v;
#pragma unroll
                for (int jj = 0; jj < 8; ++jj)
                    v[jj] = (_Float16)pp[(size_t)(x * 8 + jj) * N_];
                *(half8*)(xrow + ((512 + sub * 64 + x * 16) ^ rswz)) = v;
            }
        }
    }
    __syncthreads();

    int lane = t & 63, wv = t >> 6;
    int lr = lane & 15, lh = lane >> 4;
    int swz = (lr & 7) << 4;          // row = nf*16+lr -> (row&7) == (lr&7)

    f32x4 acc[4][4];                  // [of][nf]
#pragma unroll
    for (int of = 0; of < 4; ++of) {
        int o = wv * 64 + of * 16 + lh * 4;
        f32x4 bv = {b1[o], b1[o + 1], b1[o + 2], b1[o + 3]};
#pragma unroll
        for (int nf = 0; nf < 4; ++nf) acc[of][nf] = bv;
    }
    const _Float16* w1p = W1h + (size_t)(wv * 64 + lr) * K0_ + lh * 8;
#pragma unroll
    for (int k0 = 0; k0 < K0_; k0 += 32) {
        half8 bf[4];
#pragma unroll
        for (int nf = 0; nf < 4; ++nf)
            bf[nf] = *(const half8*)(Xs + (nf * 16 + lr) * 768 + ((k0 * 2 + lh * 16) ^ swz));
#pragma unroll
        for (int of = 0; of < 4; ++of) {
            half8 af = *(const half8*)(w1p + (size_t)of * 16 * K0_ + k0);
#pragma unroll
            for (int nf = 0; nf < 4; ++nf)
                acc[of][nf] = __builtin_amdgcn_mfma_f32_16x16x32_f16(af, bf[nf], acc[of][nf], 0, 0, 0);
        }
    }
    // epilogue: relu -> fp16 -> Y1 (B,N,O1), half4 per lane
    _Float16* yb = Y1 + ((size_t)b * N_ + n0b) * O1_;
#pragma unroll
    for (int of = 0; of < 4; ++of) {
#pragma unroll
        for (int nf = 0; nf < 4; ++nf) {
            int n = nf * 16 + lr;
            int o = wv * 64 + of * 16 + lh * 4;
            half4 h;
#pragma unroll
            for (int r = 0; r < 4; ++r) h[r] = (_Float16)fmaxf(acc[of][nf][r], 0.f);
            *(half4*)(yb + (size_t)n * O1_ + o) = h;
        }
    }
}

// ---------------------------------------------------------------------------
// Kernel B: GEMM2, zero LDS, all fragments direct global 16B loads.
// Block: 256 thr / 4 waves; tile 64n x 256 o2; wave = 64o2 x 64n.
// ---------------------------------------------------------------------------
__global__ __launch_bounds__(256, 2)
void gemm2_kernel(const _Float16* __restrict__ Y1, const _Float16* __restrict__ W2h,
                  const float* __restrict__ b2, float* __restrict__ out, int b0) {
    int b = b0 + blockIdx.y;
    int n0b = blockIdx.x * 64;
    int t = threadIdx.x, lane = t & 63, wv = t >> 6;
    int lr = lane & 15, lh = lane >> 4;

    f32x4 acc[4][4];                  // [of][nf]
#pragma unroll
    for (int of = 0; of < 4; ++of) {
        int o = wv * 64 + of * 16 + lh * 4;
        f32x4 bv = {b2[o], b2[o + 1], b2[o + 2], b2[o + 3]};
#pragma unroll
        for (int nf = 0; nf < 4; ++nf) acc[of][nf] = bv;
    }
    const _Float16* ap = W2h + (size_t)(wv * 64 + lr) * O1_ + lh * 8;
    const _Float16* bp = Y1 + ((size_t)b * N_ + n0b + lr) * O1_ + lh * 8;
#pragma unroll
    for (int k0 = 0; k0 < O1_; k0 += 32) {
        half8 af[4], bf[4];
#pragma unroll
        for (int of = 0; of < 4; ++of) af[of] = *(const half8*)(ap + (size_t)of * 16 * O1_ + k0);
#pragma unroll
        for (int nf = 0; nf < 4; ++nf) bf[nf] = *(const half8*)(bp + (size_t)nf * 16 * O1_ + k0);
#pragma unroll
        for (int of = 0; of < 4; ++of)
#pragma unroll
            for (int nf = 0; nf < 4; ++nf)
                acc[of][nf] = __builtin_amdgcn_mfma_f32_16x16x32_f16(af[of], bf[nf], acc[of][nf], 0, 0, 0);
    }
    float* ob = out + (size_t)b * O2_ * N_;
#pragma unroll
    for (int of = 0; of < 4; ++of) {
#pragma unroll
        for (int r = 0; r < 4; ++r) {
            int o2 = wv * 64 + of * 16 + lh * 4 + r;
#pragma unroll
            for (int nf = 0; nf < 4; ++nf)
                ob[(size_t)o2 * N_ + n0b + nf * 16 + lr] = fmaxf(acc[of][nf][r], 0.f);
        }
    }
}

// ---------------------------------------------------------------------------
extern "C" void kernel_launch(void* const* d_in, const int* in_sizes, int n_in,
                              void* d_out, int out_size, void* d_ws, size_t ws_size,
                              hipStream_t stream) {
    const float* xyz1    = (const float*)d_in[0];
    const float* xyz2    = (const float*)d_in[1];
    const float* points1 = (const float*)d_in[2];
    const float* points2 = (const float*)d_in[3];
    const float* W1      = (const float*)d_in[4];
    const float* b1      = (const float*)d_in[5];
    const float* W2      = (const float*)d_in[6];
    const float* b2      = (const float*)d_in[7];
    float* out = (float*)d_out;
    (void)in_sizes; (void)n_in; (void)out_size;

    char* p = (char*)d_ws;
    auto alloc = [&](size_t bytes) -> char* {
        char* r = p;
        p += (bytes + 255) & ~(size_t)255;
        return r;
    };
    _Float16* W1h  = (_Float16*)alloc((size_t)O1_ * K0_ * 2);
    _Float16* W2h  = (_Float16*)alloc((size_t)O2_ * O1_ * 2);
    int*      idxb = (int*)alloc((size_t)B_ * N_ * 3 * 4);
    float*    wbuf = (float*)alloc((size_t)B_ * N_ * 3 * 4);
    _Float16* p2T  = (_Float16*)alloc((size_t)B_ * M_ * C2_ * 2);
    size_t fixed = (size_t)(p - (char*)d_ws);

    size_t p1T_bytes = (size_t)B_ * N_ * C1_ * 2;   // 16 MB
    size_t y1_full   = (size_t)B_ * N_ * O1_ * 2;   // 32 MB
    size_t y1_per_b  = (size_t)N_ * O1_ * 2;        // 2 MB

    _Float16* p1T = nullptr;
    _Float16* Y1  = nullptr;
    int G = B_;
    if (ws_size >= fixed + p1T_bytes + y1_full) {
        p1T = (_Float16*)alloc(p1T_bytes);
        Y1  = (_Float16*)alloc(y1_full);
    } else if (ws_size >= fixed + y1_full) {
        Y1 = (_Float16*)alloc(y1_full);
    } else {
        size_t avail = (ws_size > fixed) ? ws_size - fixed : y1_per_b;
        G = (int)(avail / y1_per_b);
        if (G < 1) G = 1;
        if (G > B_) G = B_;
        Y1 = (_Float16*)alloc((size_t)G * y1_per_b);
    }

    convert_w_kernel<<<dim3((O1_ * K0_ + 255) / 256), 256, 0, stream>>>(W1, W2, W1h, W2h);
    three_nn_kernel<<<dim3(N_ / 32, B_), 256, 0, stream>>>(xyz1, xyz2, idxb, wbuf);
    transpose_f16_kernel<<<dim3(M_ / 64, C2_ / 64, B_), 256, 0, stream>>>(
        points2, p2T, M_, (size_t)C2_ * M_, (size_t)M_ * C2_, C2_);
    if (p1T)
        transpose_f16_kernel<<<dim3(N_ / 64, C1_ / 64, B_), 256, 0, stream>>>(
            points1, p1T, N_, (size_t)C1_ * N_, (size_t)N_ * C1_, C1_);

    if (G >= B_) {
        gemm1_fused_kernel<<<dim3(N_ / 64, B_), 256, 0, stream>>>(
            p2T, idxb, wbuf, points1, p1T, W1h, b1, Y1, 0);
        gemm2_kernel<<<dim3(N_ / 64, B_), 256, 0, stream>>>(Y1, W2h, b2, out, 0);
    } else {
        for (int b0 = 0; b0 < B_; b0 += G) {
            int gc = (B_ - b0 < G) ? (B_ - b0) : G;
            gemm1_fused_kernel<<<dim3(N_ / 64, gc), 256, 0, stream>>>(
                p2T, idxb, wbuf, points1, p1T, W1h, b1, Y1, b0);
            gemm2_kernel<<<dim3(N_ / 64, gc), 256, 0, stream>>>(Y1, W2h, b2, out, b0);
        }
    }
}

// Round 8
// 198.543 us; speedup vs baseline: 1.1823x; 1.1823x over previous
//
#include <hip/hip_runtime.h>

#define B_  16
#define N_  4096
#define M_  1024
#define C1_ 128
#define C2_ 256
#define K0_ 384   // C2 + C1
#define O1_ 256
#define O2_ 256

typedef _Float16 half4  __attribute__((ext_vector_type(4)));
typedef _Float16 half8  __attribute__((ext_vector_type(8)));
typedef float    f32x4  __attribute__((ext_vector_type(4)));

// Xs swizzle: row stride 768B (≡0 mod 128). Slot(bits 4-6) = kb<4:6> ^ (row&7)
// ^ ((kb>>7)&3)<<1. Every 8-consecutive-lane group of all read/write patterns
// covers 8 distinct 16B slots -> conflict-free (see R5 post-mortem).
__device__ __forceinline__ int swzX(int row, int kb) {
    return row * 768 + (kb ^ ((row & 7) << 4) ^ (((kb >> 7) & 3) << 5));
}
// Ys swizzle: row stride 512B; reads/writes have kb constant per 8-lane group,
// rows consecutive -> (row&7)<<4 alone suffices.
__device__ __forceinline__ int swzY(int row, int kb) {
    return row * 512 + (kb ^ ((row & 7) << 4));
}

// ---------------------------------------------------------------------------
// prep: z=0 three_nn (v4, unchanged math) | z=1 points2->p2T transpose |
// z=2 W1/W2 fp32->fp16. One launch for all pre-processing.
// ---------------------------------------------------------------------------
__global__ __launch_bounds__(256)
void prep_kernel(const float* __restrict__ xyz1, const float* __restrict__ xyz2,
                 const float* __restrict__ points2,
                 const float* __restrict__ W1, const float* __restrict__ W2,
                 int* __restrict__ idxb, float* __restrict__ wb,
                 _Float16* __restrict__ p2T,
                 _Float16* __restrict__ W1h, _Float16* __restrict__ W2h) {
    __shared__ __align__(16) char smem[16640];
    int t = threadIdx.x;

    if (blockIdx.z == 0) {
        // ---------------- three_nn ----------------
        float* pts = (float*)smem;            // 8 chunks x 128 pts x 4 floats (+4 pad)
        int b = blockIdx.y;
        {
            const float* src = xyz2 + (size_t)b * 3 * M_;
            int m0 = t * 4;
            f32x4 xv = *(const f32x4*)(src + m0);
            f32x4 yv = *(const f32x4*)(src + M_ + m0);
            f32x4 zv = *(const f32x4*)(src + 2 * M_ + m0);
            float* dst = pts + (m0 >> 7) * 516 + (m0 & 127) * 4;
#pragma unroll
            for (int jj = 0; jj < 4; ++jj) {
                f32x4 o = {xv[jj], yv[jj], zv[jj],
                           fmaf(xv[jj], xv[jj], fmaf(yv[jj], yv[jj], zv[jj] * zv[jj]))};
                *(f32x4*)(dst + jj * 4) = o;
            }
        }
        __syncthreads();
        int lane = t & 63;
        int c = lane & 7;
        int q = ((t >> 6) << 3) + (lane >> 3);
        int n = blockIdx.x * 32 + q;
        const float* qp = xyz1 + (size_t)b * 3 * N_;
        float px = qp[n], py = qp[N_ + n], pz = qp[2 * N_ + n];
        float px2 = -2.f * px, py2 = -2.f * py, pz2 = -2.f * pz;
        const float* base = pts + c * 516;
        float b0 = 1e30f, b1v = 1e30f, b2v = 1e30f;
        int i0 = 0, i1 = 0, i2 = 0;
        int mb = c * 128;
#pragma unroll 4
        for (int i = 0; i < 128; ++i) {
            f32x4 pv = *(const f32x4*)(base + i * 4);
            float d = fmaf(pv[0], px2, fmaf(pv[1], py2, fmaf(pv[2], pz2, pv[3])));
            int m = mb + i;
            bool c0 = d < b0, c1 = d < b1v, c2 = d < b2v;
            float nb1 = __builtin_amdgcn_fmed3f(d, b0, b1v);
            float nb2 = __builtin_amdgcn_fmed3f(d, b1v, b2v);
            i2 = c1 ? i1 : (c2 ? m : i2);
            i1 = c0 ? i0 : (c1 ? m : i1);
            i0 = c0 ? m : i0;
            b0 = fminf(b0, d);
            b1v = nb1; b2v = nb2;
        }
#pragma unroll
        for (int st = 1; st <= 4; st <<= 1) {
            float d0 = __shfl_xor(b0, st, 64);  int j0 = __shfl_xor(i0, st, 64);
            float d1 = __shfl_xor(b1v, st, 64); int j1 = __shfl_xor(i1, st, 64);
            float d2 = __shfl_xor(b2v, st, 64); int j2 = __shfl_xor(i2, st, 64);
#pragma unroll
            for (int e = 0; e < 3; ++e) {
                float d = (e == 0) ? d0 : (e == 1) ? d1 : d2;
                int   m = (e == 0) ? j0 : (e == 1) ? j1 : j2;
                bool c0 = d < b0, c1 = d < b1v, c2 = d < b2v;
                float nb1 = __builtin_amdgcn_fmed3f(d, b0, b1v);
                float nb2 = __builtin_amdgcn_fmed3f(d, b1v, b2v);
                i2 = c1 ? i1 : (c2 ? m : i2);
                i1 = c0 ? i0 : (c1 ? m : i1);
                i0 = c0 ? m : i0;
                b0 = fminf(b0, d);
                b1v = nb1; b2v = nb2;
            }
        }
        if ((lane & 7) == 0) {
            float sq1 = fmaf(px, px, fmaf(py, py, pz * pz));
            float e0 = fmaxf(sqrtf(fmaxf(b0 + sq1, 1e-20f)), 1e-10f);
            float e1 = fmaxf(sqrtf(fmaxf(b1v + sq1, 1e-20f)), 1e-10f);
            float e2 = fmaxf(sqrtf(fmaxf(b2v + sq1, 1e-20f)), 1e-10f);
            float r0 = 1.f / e0, r1 = 1.f / e1, r2 = 1.f / e2;
            float s = r0 + r1 + r2;
            size_t j = ((size_t)b * N_ + n) * 3;
            idxb[j] = i0; idxb[j + 1] = i1; idxb[j + 2] = i2;
            wb[j] = r0 / s; wb[j + 1] = r1 / s; wb[j + 2] = r2 / s;
        }
    } else if (blockIdx.z == 1) {
        // ---------------- points2 (B,C2,M) -> p2T (B,M,C2) fp16 ----------------
        if (blockIdx.x >= 64) return;
        float (*tile)[65] = (float(*)[65])smem;
        int nb = (blockIdx.x & 15) * 64, cb = (blockIdx.x >> 4) * 64;
        const float* ib = points2 + (size_t)blockIdx.y * C2_ * M_;
#pragma unroll
        for (int r = 0; r < 16; ++r) {
            int cc = r * 4 + (t >> 6);
            tile[cc][t & 63] = ib[(size_t)(cb + cc) * M_ + nb + (t & 63)];
        }
        __syncthreads();
        _Float16* ob = p2T + (size_t)blockIdx.y * M_ * C2_;
#pragma unroll
        for (int pass = 0; pass < 2; ++pass) {
            int id = pass * 256 + t;
            int nl = id >> 3;
            int c8 = (id & 7) * 8;
            half8 v;
#pragma unroll
            for (int jj = 0; jj < 8; ++jj) v[jj] = (_Float16)tile[c8 + jj][nl];
            *(half8*)(ob + (size_t)(nb + nl) * C2_ + cb + c8) = v;
        }
    } else {
        // ---------------- W convert ----------------
        int id = blockIdx.y * 128 + blockIdx.x;
        if (id >= 384) return;
        int g = id * 256 + t;
        if (g < O1_ * K0_) W1h[g] = (_Float16)W1[g];
        if (g < O2_ * O1_) W2h[g] = (_Float16)W2[g];
    }
}

// ---------------------------------------------------------------------------
// Fused v5: stage X (interp fp32-accum + strided points1) into swizzled 48KB
// LDS -> GEMM1(relu) -> Ys (ALIASES Xs; sync-guarded) -> GEMM2(relu) -> out.
// 256 thr / 4 waves, tile 64n; wave = 64o x 64n both phases. Manual k+1
// fragment prefetch forces double-buffered registers (ILP) — R5's VGPR=68
// collapse is the thing this is fixing. 48KB -> 3 blocks/CU, VGPR cap ~170.
// ---------------------------------------------------------------------------
__global__ __launch_bounds__(256, 3)
void fused_mlp_kernel(const _Float16* __restrict__ p2T, const int* __restrict__ idxb,
                      const float* __restrict__ wb, const float* __restrict__ points1,
                      const _Float16* __restrict__ W1h, const float* __restrict__ b1,
                      const _Float16* __restrict__ W2h, const float* __restrict__ b2,
                      float* __restrict__ out) {
    __shared__ __align__(16) char Xs[64 * 768];
    int b = blockIdx.y;
    int n0b = blockIdx.x * 64;
    int t = threadIdx.x;

    // ---- stage X: 4 threads/row (sub = quarter of the channel range) ----
    {
        int row = t >> 2, sub = t & 3;
        size_t j = ((size_t)b * N_ + n0b + row) * 3;
        int i0 = idxb[j], i1 = idxb[j + 1], i2 = idxb[j + 2];
        float w0 = wb[j], w1 = wb[j + 1], w2 = wb[j + 2];
        const _Float16* pb = p2T + (size_t)b * M_ * C2_;
        const half8* q0 = (const half8*)(pb + (size_t)i0 * C2_ + sub * 64);
        const half8* q1 = (const half8*)(pb + (size_t)i1 * C2_ + sub * 64);
        const half8* q2 = (const half8*)(pb + (size_t)i2 * C2_ + sub * 64);
#pragma unroll
        for (int x = 0; x < 8; ++x) {
            half8 a0 = q0[x], a1 = q1[x], a2 = q2[x];
            half8 v;
#pragma unroll
            for (int jj = 0; jj < 8; ++jj)
                v[jj] = (_Float16)(w0 * (float)a0[jj] + w1 * (float)a1[jj]
                                 + w2 * (float)a2[jj]);
            *(half8*)(Xs + swzX(row, sub * 128 + x * 16)) = v;
        }
        const float* pp = points1 + ((size_t)b * C1_ + sub * 32) * N_ + n0b + row;
#pragma unroll
        for (int x = 0; x < 4; ++x) {
            half8 v;
#pragma unroll
            for (int jj = 0; jj < 8; ++jj)
                v[jj] = (_Float16)pp[(size_t)(x * 8 + jj) * N_];
            *(half8*)(Xs + swzX(row, 512 + sub * 64 + x * 16)) = v;
        }
    }
    __syncthreads();

    int lane = t & 63, wv = t >> 6;
    int lr = lane & 15, lh = lane >> 4;

    // ---- phase 1: Y1 = relu(W1 * X^T + b1); wave = 64o x 64n ----
    f32x4 acc[4][4];                  // [of][nf]
#pragma unroll
    for (int of = 0; of < 4; ++of) {
        int o = wv * 64 + of * 16 + lh * 4;
        f32x4 bv = {b1[o], b1[o + 1], b1[o + 2], b1[o + 3]};
#pragma unroll
        for (int nf = 0; nf < 4; ++nf) acc[of][nf] = bv;
    }
    const _Float16* w1p = W1h + (size_t)(wv * 64 + lr) * K0_ + lh * 8;
    half8 af[4], bf[4];
#pragma unroll
    for (int of = 0; of < 4; ++of) af[of] = *(const half8*)(w1p + (size_t)of * 16 * K0_);
#pragma unroll
    for (int nf = 0; nf < 4; ++nf) bf[nf] = *(const half8*)(Xs + swzX(nf * 16 + lr, lh * 16));
#pragma unroll
    for (int ks = 0; ks < 12; ++ks) {
        half8 naf[4], nbf[4];
        if (ks < 11) {
            int kk = (ks + 1) * 32;
#pragma unroll
            for (int of = 0; of < 4; ++of)
                naf[of] = *(const half8*)(w1p + (size_t)of * 16 * K0_ + kk);
#pragma unroll
            for (int nf = 0; nf < 4; ++nf)
                nbf[nf] = *(const half8*)(Xs + swzX(nf * 16 + lr, kk * 2 + lh * 16));
        }
#pragma unroll
        for (int of = 0; of < 4; ++of)
#pragma unroll
            for (int nf = 0; nf < 4; ++nf)
                acc[of][nf] = __builtin_amdgcn_mfma_f32_16x16x32_f16(af[of], bf[nf], acc[of][nf], 0, 0, 0);
        if (ks < 11) {
#pragma unroll
            for (int of = 0; of < 4; ++of) af[of] = naf[of];
#pragma unroll
            for (int nf = 0; nf < 4; ++nf) bf[nf] = nbf[nf];
        }
    }
    __syncthreads();                  // all Xs reads done before Ys overwrites

    // ---- epilogue 1: relu -> fp16 -> Ys (aliases Xs) ----
    char* Ys = Xs;
#pragma unroll
    for (int of = 0; of < 4; ++of) {
#pragma unroll
        for (int nf = 0; nf < 4; ++nf) {
            int rn = nf * 16 + lr;
            int obyte = (wv * 64 + of * 16 + lh * 4) * 2;
            half4 h;
#pragma unroll
            for (int r = 0; r < 4; ++r) h[r] = (_Float16)fmaxf(acc[of][nf][r], 0.f);
            *(half4*)(Ys + swzY(rn, obyte)) = h;
        }
    }
    __syncthreads();

    // ---- phase 2: out = relu(W2 * Y1^T + b2); wave = 64o2 x 64n ----
    f32x4 acc2[4][4];
#pragma unroll
    for (int of = 0; of < 4; ++of) {
        int o = wv * 64 + of * 16 + lh * 4;
        f32x4 bv = {b2[o], b2[o + 1], b2[o + 2], b2[o + 3]};
#pragma unroll
        for (int nf = 0; nf < 4; ++nf) acc2[of][nf] = bv;
    }
    const _Float16* w2p = W2h + (size_t)(wv * 64 + lr) * O1_ + lh * 8;
    half8 af2[4], bf2[4];
#pragma unroll
    for (int of = 0; of < 4; ++of) af2[of] = *(const half8*)(w2p + (size_t)of * 16 * O1_);
#pragma unroll
    for (int nf = 0; nf < 4; ++nf) bf2[nf] = *(const half8*)(Ys + swzY(nf * 16 + lr, lh * 16));
#pragma unroll
    for (int ks = 0; ks < 8; ++ks) {
        half8 naf[4], nbf[4];
        if (ks < 7) {
            int kk = (ks + 1) * 32;
#pragma unroll
            for (int of = 0; of < 4; ++of)
                naf[of] = *(const half8*)(w2p + (size_t)of * 16 * O1_ + kk);
#pragma unroll
            for (int nf = 0; nf < 4; ++nf)
                nbf[nf] = *(const half8*)(Ys + swzY(nf * 16 + lr, kk * 2 + lh * 16));
        }
#pragma unroll
        for (int of = 0; of < 4; ++of)
#pragma unroll
            for (int nf = 0; nf < 4; ++nf)
                acc2[of][nf] = __builtin_amdgcn_mfma_f32_16x16x32_f16(af2[of], bf2[nf], acc2[of][nf], 0, 0, 0);
        if (ks < 7) {
#pragma unroll
            for (int of = 0; of < 4; ++of) af2[of] = naf[of];
#pragma unroll
            for (int nf = 0; nf < 4; ++nf) bf2[nf] = nbf[nf];
        }
    }
    float* ob = out + (size_t)b * O2_ * N_;
#pragma unroll
    for (int of = 0; of < 4; ++of) {
#pragma unroll
        for (int r = 0; r < 4; ++r) {
            int o2 = wv * 64 + of * 16 + lh * 4 + r;
#pragma unroll
            for (int nf = 0; nf < 4; ++nf)
                ob[(size_t)o2 * N_ + n0b + nf * 16 + lr] = fmaxf(acc2[of][nf][r], 0.f);
        }
    }
}

// ---------------------------------------------------------------------------
extern "C" void kernel_launch(void* const* d_in, const int* in_sizes, int n_in,
                              void* d_out, int out_size, void* d_ws, size_t ws_size,
                              hipStream_t stream) {
    const float* xyz1    = (const float*)d_in[0];
    const float* xyz2    = (const float*)d_in[1];
    const float* points1 = (const float*)d_in[2];
    const float* points2 = (const float*)d_in[3];
    const float* W1      = (const float*)d_in[4];
    const float* b1      = (const float*)d_in[5];
    const float* W2      = (const float*)d_in[6];
    const float* b2      = (const float*)d_in[7];
    float* out = (float*)d_out;
    (void)in_sizes; (void)n_in; (void)out_size; (void)ws_size;

    char* p = (char*)d_ws;
    auto alloc = [&](size_t bytes) -> char* {
        char* r = p;
        p += (bytes + 255) & ~(size_t)255;
        return r;
    };
    _Float16* W1h  = (_Float16*)alloc((size_t)O1_ * K0_ * 2);
    _Float16* W2h  = (_Float16*)alloc((size_t)O2_ * O1_ * 2);
    int*      idxb = (int*)alloc((size_t)B_ * N_ * 3 * 4);
    float*    wbuf = (float*)alloc((size_t)B_ * N_ * 3 * 4);
    _Float16* p2T  = (_Float16*)alloc((size_t)B_ * M_ * C2_ * 2);

    prep_kernel<<<dim3(128, 16, 3), 256, 0, stream>>>(
        xyz1, xyz2, points2, W1, W2, idxb, wbuf, p2T, W1h, W2h);
    fused_mlp_kernel<<<dim3(N_ / 64, B_), 256, 0, stream>>>(
        p2T, idxb, wbuf, points1, W1h, b1, W2h, b2, out);
}